// Round 5
// baseline (520.379 us; speedup 1.0000x reference)
//
#include <hip/hip_runtime.h>

typedef __attribute__((ext_vector_type(4))) float f32x4;
typedef __attribute__((ext_vector_type(8))) __bf16 bf16x8;
typedef unsigned short u16;

#define GAS(p) ((const __attribute__((address_space(1))) void*)(p))
#define LAS(p) ((__attribute__((address_space(3))) void*)(p))

__device__ __forceinline__ u16 f32_to_bf16(float f) {
  unsigned u = __builtin_bit_cast(unsigned, f);
  u += 0x7FFFu + ((u >> 16) & 1u);
  return (u16)(u >> 16);
}

// ---------------- elementwise f32 -> bf16 ----------------
__global__ __launch_bounds__(256) void k_convert(const float* __restrict__ X,
                                                 u16* __restrict__ Y, int n4) {
  int i = blockIdx.x * 256 + threadIdx.x;
  if (i >= n4) return;
  float4 v = ((const float4*)X)[i];
  ushort4 r;
  r.x = f32_to_bf16(v.x); r.y = f32_to_bf16(v.y);
  r.z = f32_to_bf16(v.z); r.w = f32_to_bf16(v.w);
  ((ushort4*)Y)[i] = r;
}

// ---------------- W [K][N] f32 -> WT [N][K] bf16 ----------------
__global__ __launch_bounds__(256) void k_transpose_w(const float* __restrict__ W,
                                                     u16* __restrict__ WT,
                                                     int K, int N) {
  __shared__ float tile[32][33];
  int n0 = blockIdx.x * 32, k0 = blockIdx.y * 32;
  int tx = threadIdx.x & 31, ty = threadIdx.x >> 5;
#pragma unroll
  for (int r = 0; r < 4; ++r)
    tile[ty + r * 8][tx] = W[(long)(k0 + ty + r * 8) * N + n0 + tx];
  __syncthreads();
#pragma unroll
  for (int r = 0; r < 4; ++r)
    WT[(long)(n0 + ty + r * 8) * K + k0 + tx] = f32_to_bf16(tile[tx][ty + r * 8]);
}

// ---------------- V [BH][S][128] bf16 -> VT [BH][128][S] bf16 ----------------
__global__ __launch_bounds__(256) void k_transpose_v(const u16* __restrict__ V,
                                                     u16* __restrict__ VT) {
  __shared__ u16 tile[32][34];
  int s0 = blockIdx.x * 32, d0 = blockIdx.y * 32, bh = blockIdx.z;
  int tx = threadIdx.x & 31, ty = threadIdx.x >> 5;
  const u16* Vb = V + (long)bh * 2048 * 128;
  u16* VTb = VT + (long)bh * 128 * 2048;
#pragma unroll
  for (int r = 0; r < 4; ++r)
    tile[ty + r * 8][tx] = Vb[(long)(s0 + ty + r * 8) * 128 + d0 + tx];
  __syncthreads();
#pragma unroll
  for (int r = 0; r < 4; ++r)
    VTb[(long)(d0 + ty + r * 8) * 2048 + s0 + tx] = tile[tx][ty + r * 8];
}

// ---------------- m97-structure bf16 GEMM, 128x128 tile, BK=32 ----------------
template <int EPI>
__global__ __launch_bounds__(256) void k_gemm(
    const u16* __restrict__ A, const u16* __restrict__ BT,
    const float* __restrict__ bias,
    u16* __restrict__ Qo, u16* __restrict__ Ko, u16* __restrict__ Vo,
    float* __restrict__ Cout, int M, int N, int K) {
  __shared__ alignas(16) u16 As[128 * 32];
  __shared__ alignas(16) u16 Bs[128 * 32];
  const int t = threadIdx.x;
  const int wave = t >> 6, lane = t & 63;
  const int wr = wave >> 1, wc = wave & 1;
  const int l15 = lane & 15, l4 = lane >> 4;
  const int brow = blockIdx.x * 128, bcol = blockIdx.y * 128;

  const f32x4 fzero = {0.f, 0.f, 0.f, 0.f};
  f32x4 acc[4][4];
#pragma unroll
  for (int m = 0; m < 4; ++m)
#pragma unroll
    for (int n = 0; n < 4; ++n) acc[m][n] = fzero;

  const int c0 = wave * 64 + lane;
  const int c1 = 256 + c0;
  const u16* ga0 = A + (long)(brow + (c0 >> 2)) * K + (c0 & 3) * 8;
  const u16* ga1 = A + (long)(brow + (c1 >> 2)) * K + (c1 & 3) * 8;
  const u16* gb0 = BT + (long)(bcol + (c0 >> 2)) * K + (c0 & 3) * 8;
  const u16* gb1 = BT + (long)(bcol + (c1 >> 2)) * K + (c1 & 3) * 8;
  char* lA0 = (char*)As + (wave * 64) * 16;
  char* lA1 = (char*)As + (256 + wave * 64) * 16;
  char* lB0 = (char*)Bs + (wave * 64) * 16;
  char* lB1 = (char*)Bs + (256 + wave * 64) * 16;

  for (int k0 = 0; k0 < K; k0 += 32) {
    __builtin_amdgcn_global_load_lds(GAS(ga0 + k0), LAS(lA0), 16, 0, 0);
    __builtin_amdgcn_global_load_lds(GAS(ga1 + k0), LAS(lA1), 16, 0, 0);
    __builtin_amdgcn_global_load_lds(GAS(gb0 + k0), LAS(lB0), 16, 0, 0);
    __builtin_amdgcn_global_load_lds(GAS(gb1 + k0), LAS(lB1), 16, 0, 0);
    __syncthreads();
    bf16x8 af[4], bf[4];
#pragma unroll
    for (int m = 0; m < 4; ++m)
      af[m] = *(const bf16x8*)(As + (wr * 64 + m * 16 + l15) * 32 + l4 * 8);
#pragma unroll
    for (int n = 0; n < 4; ++n)
      bf[n] = *(const bf16x8*)(Bs + (wc * 64 + n * 16 + l15) * 32 + l4 * 8);
#pragma unroll
    for (int m = 0; m < 4; ++m)
#pragma unroll
      for (int n = 0; n < 4; ++n)
        acc[m][n] =
            __builtin_amdgcn_mfma_f32_16x16x32_bf16(af[m], bf[n], acc[m][n], 0, 0, 0);
    __syncthreads();
  }

  if (EPI == 0) {
    const int which = bcol >> 11;
    u16* dst = (which == 0) ? Qo : (which == 1) ? Ko : Vo;
    const int cbase = bcol & 2047;
#pragma unroll
    for (int n = 0; n < 4; ++n) {
      int col = cbase + wc * 64 + n * 16 + l15;
      int h = col >> 7, d = col & 127;
      float bv = bias[bcol + wc * 64 + n * 16 + l15];
#pragma unroll
      for (int m = 0; m < 4; ++m) {
#pragma unroll
        for (int r = 0; r < 4; ++r) {
          int row = brow + wr * 64 + m * 16 + l4 * 4 + r;
          int b = row >> 11, s = row & 2047;
          dst[(((long)(b * 16 + h)) * 2048 + s) * 128 + d] =
              f32_to_bf16(acc[m][n][r] + bv);
        }
      }
    }
  } else {
#pragma unroll
    for (int m = 0; m < 4; ++m) {
#pragma unroll
      for (int r = 0; r < 4; ++r) {
        int row = brow + wr * 64 + m * 16 + l4 * 4 + r;
#pragma unroll
        for (int n = 0; n < 4; ++n) {
          int col = bcol + wc * 64 + n * 16 + l15;
          Cout[(long)row * N + col] = acc[m][n][r] + bias[col];
        }
      }
    }
  }
}

// ---------------- flash attention with ALiBi, causal ----------------
// 256-thread blocks = 4 INDEPENDENT waves, no barriers. Wave w owns q-tile
// (qgroup*4+w) of head bh; 16 q-rows per wave; KV tiles of 64.
// NO max-tracking: softmax(s) = exp2(s')/sum(exp2(s')) with m=0 is exact
// (scores are O(+-10) in log2 units; f32 exp2 can't overflow, masked/distant
// entries underflow to exactly 0). This removes both shuffle-reduce chains,
// the cross-iteration mrun dependency, and the O-rescale from the loop.
// Sum-reduce is deferred to the epilogue (per-lane partials in-loop).
// launch_bounds(256,4): (256,6) forced VGPR->40 and spilled 1.2 GB (R3).
__global__ __launch_bounds__(256, 4) void k_attn(const u16* __restrict__ Q,
                                                 const u16* __restrict__ Kp,
                                                 const u16* __restrict__ VT,
                                                 u16* __restrict__ Oa) {
  __shared__ alignas(16) u16 Pl[4][2][16 * 64];  // per-wave double-buffered P
  const int bh = blockIdx.x & 31;
  const int qgroup = 31 - ((int)blockIdx.x >> 5);  // heavy-first LPT
  const int b = bh >> 4, h = bh & 15;
  const int wave = threadIdx.x >> 6, lane = threadIdx.x & 63;
  const int l15 = lane & 15, l4 = lane >> 4;
  const float LOG2E = 1.4426950408889634f;
  const float scale = 0.08838834764831845f * LOG2E;  // (1/sqrt(128))*log2e
  const float slope = exp2f(-0.5f * (float)h) * LOG2E;

  const int qtile = qgroup * 4 + wave;
  const int q0 = qtile * 16;
  const u16* Qb = Q + ((long)bh * 2048 + q0 + l15) * 128;
  bf16x8 qf[4];
#pragma unroll
  for (int kk = 0; kk < 4; ++kk) qf[kk] = *(const bf16x8*)(Qb + kk * 32 + l4 * 8);

  const u16* Kb = Kp + (long)bh * 2048 * 128;
  const u16* Vb = VT + (long)bh * 128 * 2048;

  float rs[4];  // per-lane partial row-sums (reduced once at the end)
  f32x4 O[8];
  const f32x4 fzero = {0.f, 0.f, 0.f, 0.f};
#pragma unroll
  for (int r = 0; r < 4; ++r) rs[r] = 0.f;
#pragma unroll
  for (int nb = 0; nb < 8; ++nb) O[nb] = fzero;

  const int irow = q0 + l4 * 4;  // this lane's 4 rows are irow+r
  const int jtmax = (q0 + 15) >> 6;
  for (int jt = 0; jt <= jtmax; ++jt) {
    const int j0 = jt * 64;
    u16* Pw = Pl[wave][jt & 1];
    // ---- QK^T -> P = exp2(s*scale' - slope'*(i-j)) straight to LDS ----
#pragma unroll
    for (int cb = 0; cb < 4; ++cb) {
      f32x4 sa = fzero;
      const u16* kp = Kb + (long)(j0 + cb * 16 + l15) * 128 + l4 * 8;
#pragma unroll
      for (int kk = 0; kk < 4; ++kk) {
        bf16x8 kf = *(const bf16x8*)(kp + kk * 32);
        sa = __builtin_amdgcn_mfma_f32_16x16x32_bf16(qf[kk], kf, sa, 0, 0, 0);
      }
      const int j = j0 + cb * 16 + l15;
#pragma unroll
      for (int r = 0; r < 4; ++r) {
        int i = irow + r;
        float s = sa[r] * scale - slope * (float)(i - j);
        float p = __builtin_amdgcn_exp2f((j <= i) ? s : -1e30f);
        rs[r] += p;
        int rloc = l4 * 4 + r;
        int cbyte = (cb * 16 + l15) * 2;
        *(u16*)((char*)Pw + rloc * 128 + (cbyte ^ ((rloc & 7) << 4))) =
            f32_to_bf16(p);
      }
    }
    // ---- read P as A-fragments (same-wave RAW; compiler waits lgkmcnt) ----
    bf16x8 pf0 = *(const bf16x8*)((char*)Pw + l15 * 128 +
                                  ((l4 * 16) ^ ((l15 & 7) << 4)));
    bf16x8 pf1 = *(const bf16x8*)((char*)Pw + l15 * 128 +
                                  ((64 + l4 * 16) ^ ((l15 & 7) << 4)));
    // ---- PV: V^T fragments straight from global (L2-resident) ----
#pragma unroll
    for (int nb = 0; nb < 8; ++nb) {
      const u16* vp = Vb + (long)(nb * 16 + l15) * 2048 + j0 + l4 * 8;
      bf16x8 v0 = *(const bf16x8*)(vp);
      bf16x8 v1 = *(const bf16x8*)(vp + 32);
      O[nb] = __builtin_amdgcn_mfma_f32_16x16x32_bf16(pf0, v0, O[nb], 0, 0, 0);
      O[nb] = __builtin_amdgcn_mfma_f32_16x16x32_bf16(pf1, v1, O[nb], 0, 0, 0);
    }
  }
  // ---- epilogue: one cross-lane sum-reduce, normalize, store ----
#pragma unroll
  for (int r = 0; r < 4; ++r) {
    float v = rs[r];
    v += __shfl_xor(v, 1);
    v += __shfl_xor(v, 2);
    v += __shfl_xor(v, 4);
    v += __shfl_xor(v, 8);
    float inv = 1.f / v;
    int i = irow + r;
    u16* op = Oa + ((long)b * 2048 + i) * 2048 + h * 128;
#pragma unroll
    for (int nb = 0; nb < 8; ++nb) op[nb * 16 + l15] = f32_to_bf16(O[nb][r] * inv);
  }
}

extern "C" void kernel_launch(void* const* d_in, const int* in_sizes, int n_in,
                              void* d_out, int out_size, void* d_ws, size_t ws_size,
                              hipStream_t stream) {
  const float* x = (const float*)d_in[0];
  const float* Wqkv = (const float*)d_in[1];
  const float* bqkv = (const float*)d_in[2];
  const float* Wo = (const float*)d_in[3];
  const float* bo = (const float*)d_in[4];
  float* out = (float*)d_out;

  char* ws = (char*)d_ws;
  u16* xb = (u16*)(ws);
  u16* VTb = (u16*)(ws);  // aliases xb (xb dead after GEMM1)
  u16* WqkvT = (u16*)(ws + 16777216);
  u16* attn_out = (u16*)(ws + 16777216);  // aliases WqkvT (dead after GEMM1)
  u16* WoT = (u16*)(ws + 16777216 + 25165824);
  u16* Qb = (u16*)(ws + 50331648);
  u16* Kb = (u16*)(ws + 67108864);
  u16* Vb = (u16*)(ws + 83886080);

  k_convert<<<8192, 256, 0, stream>>>(x, xb, 8388608 / 4);
  k_transpose_w<<<dim3(192, 64), 256, 0, stream>>>(Wqkv, WqkvT, 2048, 6144);
  k_transpose_w<<<dim3(64, 64), 256, 0, stream>>>(Wo, WoT, 2048, 2048);
  k_gemm<0><<<dim3(32, 48), 256, 0, stream>>>(xb, WqkvT, bqkv, Qb, Kb, Vb,
                                              nullptr, 4096, 6144, 2048);
  k_transpose_v<<<dim3(64, 4, 32), 256, 0, stream>>>(Vb, VTb);
  k_attn<<<dim3(1024), 256, 0, stream>>>(Qb, Kb, VTb, attn_out);
  k_gemm<1><<<dim3(32, 16), 256, 0, stream>>>(attn_out, WoT, bo, nullptr,
                                              nullptr, nullptr, out, 4096, 2048,
                                              2048);
}

// Round 6
// 462.544 us; speedup vs baseline: 1.1250x; 1.1250x over previous
//
#include <hip/hip_runtime.h>

typedef __attribute__((ext_vector_type(4))) float f32x4;
typedef __attribute__((ext_vector_type(8))) __bf16 bf16x8;
typedef unsigned short u16;

#define GAS(p) ((const __attribute__((address_space(1))) void*)(p))
#define LAS(p) ((__attribute__((address_space(3))) void*)(p))

__device__ __forceinline__ u16 f32_to_bf16(float f) {
  unsigned u = __builtin_bit_cast(unsigned, f);
  u += 0x7FFFu + ((u >> 16) & 1u);
  return (u16)(u >> 16);
}

// ---------------- elementwise f32 -> bf16 ----------------
__global__ __launch_bounds__(256) void k_convert(const float* __restrict__ X,
                                                 u16* __restrict__ Y, int n4) {
  int i = blockIdx.x * 256 + threadIdx.x;
  if (i >= n4) return;
  float4 v = ((const float4*)X)[i];
  ushort4 r;
  r.x = f32_to_bf16(v.x); r.y = f32_to_bf16(v.y);
  r.z = f32_to_bf16(v.z); r.w = f32_to_bf16(v.w);
  ((ushort4*)Y)[i] = r;
}

// ---------------- W [K][N] f32 -> WT [N][K] bf16 ----------------
__global__ __launch_bounds__(256) void k_transpose_w(const float* __restrict__ W,
                                                     u16* __restrict__ WT,
                                                     int K, int N) {
  __shared__ float tile[32][33];
  int n0 = blockIdx.x * 32, k0 = blockIdx.y * 32;
  int tx = threadIdx.x & 31, ty = threadIdx.x >> 5;
#pragma unroll
  for (int r = 0; r < 4; ++r)
    tile[ty + r * 8][tx] = W[(long)(k0 + ty + r * 8) * N + n0 + tx];
  __syncthreads();
#pragma unroll
  for (int r = 0; r < 4; ++r)
    WT[(long)(n0 + ty + r * 8) * K + k0 + tx] = f32_to_bf16(tile[tx][ty + r * 8]);
}

// ---------------- V [BH][S][128] bf16 -> VT [BH][128][S] bf16 ----------------
__global__ __launch_bounds__(256) void k_transpose_v(const u16* __restrict__ V,
                                                     u16* __restrict__ VT) {
  __shared__ u16 tile[32][34];
  int s0 = blockIdx.x * 32, d0 = blockIdx.y * 32, bh = blockIdx.z;
  int tx = threadIdx.x & 31, ty = threadIdx.x >> 5;
  const u16* Vb = V + (long)bh * 2048 * 128;
  u16* VTb = VT + (long)bh * 128 * 2048;
#pragma unroll
  for (int r = 0; r < 4; ++r)
    tile[ty + r * 8][tx] = Vb[(long)(s0 + ty + r * 8) * 128 + d0 + tx];
  __syncthreads();
#pragma unroll
  for (int r = 0; r < 4; ++r)
    VTb[(long)(d0 + ty + r * 8) * 2048 + s0 + tx] = tile[tx][ty + r * 8];
}

// ---------------- m97-structure bf16 GEMM, 128x128 tile, BK=32 ----------------
template <int EPI>
__global__ __launch_bounds__(256) void k_gemm(
    const u16* __restrict__ A, const u16* __restrict__ BT,
    const float* __restrict__ bias,
    u16* __restrict__ Qo, u16* __restrict__ Ko, u16* __restrict__ Vo,
    float* __restrict__ Cout, int M, int N, int K) {
  __shared__ alignas(16) u16 As[128 * 32];
  __shared__ alignas(16) u16 Bs[128 * 32];
  const int t = threadIdx.x;
  const int wave = t >> 6, lane = t & 63;
  const int wr = wave >> 1, wc = wave & 1;
  const int l15 = lane & 15, l4 = lane >> 4;
  const int brow = blockIdx.x * 128, bcol = blockIdx.y * 128;

  const f32x4 fzero = {0.f, 0.f, 0.f, 0.f};
  f32x4 acc[4][4];
#pragma unroll
  for (int m = 0; m < 4; ++m)
#pragma unroll
    for (int n = 0; n < 4; ++n) acc[m][n] = fzero;

  const int c0 = wave * 64 + lane;
  const int c1 = 256 + c0;
  const u16* ga0 = A + (long)(brow + (c0 >> 2)) * K + (c0 & 3) * 8;
  const u16* ga1 = A + (long)(brow + (c1 >> 2)) * K + (c1 & 3) * 8;
  const u16* gb0 = BT + (long)(bcol + (c0 >> 2)) * K + (c0 & 3) * 8;
  const u16* gb1 = BT + (long)(bcol + (c1 >> 2)) * K + (c1 & 3) * 8;
  char* lA0 = (char*)As + (wave * 64) * 16;
  char* lA1 = (char*)As + (256 + wave * 64) * 16;
  char* lB0 = (char*)Bs + (wave * 64) * 16;
  char* lB1 = (char*)Bs + (256 + wave * 64) * 16;

  for (int k0 = 0; k0 < K; k0 += 32) {
    __builtin_amdgcn_global_load_lds(GAS(ga0 + k0), LAS(lA0), 16, 0, 0);
    __builtin_amdgcn_global_load_lds(GAS(ga1 + k0), LAS(lA1), 16, 0, 0);
    __builtin_amdgcn_global_load_lds(GAS(gb0 + k0), LAS(lB0), 16, 0, 0);
    __builtin_amdgcn_global_load_lds(GAS(gb1 + k0), LAS(lB1), 16, 0, 0);
    __syncthreads();
    bf16x8 af[4], bf[4];
#pragma unroll
    for (int m = 0; m < 4; ++m)
      af[m] = *(const bf16x8*)(As + (wr * 64 + m * 16 + l15) * 32 + l4 * 8);
#pragma unroll
    for (int n = 0; n < 4; ++n)
      bf[n] = *(const bf16x8*)(Bs + (wc * 64 + n * 16 + l15) * 32 + l4 * 8);
#pragma unroll
    for (int m = 0; m < 4; ++m)
#pragma unroll
      for (int n = 0; n < 4; ++n)
        acc[m][n] =
            __builtin_amdgcn_mfma_f32_16x16x32_bf16(af[m], bf[n], acc[m][n], 0, 0, 0);
    __syncthreads();
  }

  if (EPI == 0) {
    const int which = bcol >> 11;
    u16* dst = (which == 0) ? Qo : (which == 1) ? Ko : Vo;
    const int cbase = bcol & 2047;
#pragma unroll
    for (int n = 0; n < 4; ++n) {
      int col = cbase + wc * 64 + n * 16 + l15;
      int h = col >> 7, d = col & 127;
      float bv = bias[bcol + wc * 64 + n * 16 + l15];
#pragma unroll
      for (int m = 0; m < 4; ++m) {
#pragma unroll
        for (int r = 0; r < 4; ++r) {
          int row = brow + wr * 64 + m * 16 + l4 * 4 + r;
          int b = row >> 11, s = row & 2047;
          dst[(((long)(b * 16 + h)) * 2048 + s) * 128 + d] =
              f32_to_bf16(acc[m][n][r] + bv);
        }
      }
    }
  } else {
#pragma unroll
    for (int m = 0; m < 4; ++m) {
#pragma unroll
      for (int r = 0; r < 4; ++r) {
        int row = brow + wr * 64 + m * 16 + l4 * 4 + r;
#pragma unroll
        for (int n = 0; n < 4; ++n) {
          int col = bcol + wc * 64 + n * 16 + l15;
          Cout[(long)row * N + col] = acc[m][n][r] + bias[col];
        }
      }
    }
  }
}

// ---------------- flash attention with ALiBi, causal ----------------
// 2-way KV-split: each 4-wave block owns 2 q-tile units; unit u = waves
// {2u, 2u+1}. Wave ha=wave&1 processes KV tiles jt = ha, ha+2, ... (balanced).
// Because softmax uses fixed m=0 (exact here: scores are O(+-10) in log2
// units, f32 exp2 can't overflow, masked entries underflow to 0), partials
// combine by PLAIN ADDITION: O_tot = O_A + O_B, l_tot = l_A + l_B.
// Combine via LDS reusing the (then dead) P buffers; 2 barriers per block.
// grid = 2048: bh = b&31 (same-bh -> same XCD), qgroup = 63-(b>>5) heavy-
// first, qtile = qgroup*2 + u. 8192 waves total = 8/SIMD TLP ceiling
// (R5's 4096/4 was the latency-bound cap; occupancy was 28%).
// launch_bounds(256,4): (256,6) forced VGPR->40 and spilled 1.2 GB (R3).
__global__ __launch_bounds__(256, 4) void k_attn(const u16* __restrict__ Q,
                                                 const u16* __restrict__ Kp,
                                                 const u16* __restrict__ VT,
                                                 u16* __restrict__ Oa) {
  __shared__ alignas(16) u16 Pl[4][2][16 * 64];  // per-wave double-buffered P
  __shared__ float Rc[32];                       // per-unit partial row-sums
  const int b = blockIdx.x;
  const int bh = b & 31;
  const int qgroup = 63 - (b >> 5);  // heavy-first LPT
  const int bb = bh >> 4, h = bh & 15;
  const int wave = threadIdx.x >> 6, lane = threadIdx.x & 63;
  const int u = wave >> 1, ha = wave & 1;
  const int l15 = lane & 15, l4 = lane >> 4;
  const float LOG2E = 1.4426950408889634f;
  const float scale = 0.08838834764831845f * LOG2E;  // (1/sqrt(128))*log2e
  const float slope = exp2f(-0.5f * (float)h) * LOG2E;

  const int qtile = qgroup * 2 + u;
  const int q0 = qtile * 16;
  const u16* Qb = Q + ((long)bh * 2048 + q0 + l15) * 128;
  bf16x8 qf[4];
#pragma unroll
  for (int kk = 0; kk < 4; ++kk) qf[kk] = *(const bf16x8*)(Qb + kk * 32 + l4 * 8);

  const u16* Kb = Kp + (long)bh * 2048 * 128;
  const u16* Vb = VT + (long)bh * 128 * 2048;

  float rs[4];  // per-lane partial row-sums (reduced once at the end)
  f32x4 O[8];
  const f32x4 fzero = {0.f, 0.f, 0.f, 0.f};
#pragma unroll
  for (int r = 0; r < 4; ++r) rs[r] = 0.f;
#pragma unroll
  for (int nb = 0; nb < 8; ++nb) O[nb] = fzero;

  const int irow = q0 + l4 * 4;  // this lane's 4 rows are irow+r
  const int jtmax = qtile >> 2;  // last KV tile index = (q0+15)>>6
  for (int jt = ha; jt <= jtmax; jt += 2) {
    const int j0 = jt * 64;
    u16* Pw = Pl[wave][(jt >> 1) & 1];
    // ---- QK^T -> P = exp2(s*scale' - slope'*(i-j)) straight to LDS ----
#pragma unroll
    for (int cb = 0; cb < 4; ++cb) {
      f32x4 sa = fzero;
      const u16* kp = Kb + (long)(j0 + cb * 16 + l15) * 128 + l4 * 8;
#pragma unroll
      for (int kk = 0; kk < 4; ++kk) {
        bf16x8 kf = *(const bf16x8*)(kp + kk * 32);
        sa = __builtin_amdgcn_mfma_f32_16x16x32_bf16(qf[kk], kf, sa, 0, 0, 0);
      }
      const int j = j0 + cb * 16 + l15;
#pragma unroll
      for (int r = 0; r < 4; ++r) {
        int i = irow + r;
        float s = sa[r] * scale - slope * (float)(i - j);
        float p = __builtin_amdgcn_exp2f((j <= i) ? s : -1e30f);
        rs[r] += p;
        int rloc = l4 * 4 + r;
        int cbyte = (cb * 16 + l15) * 2;
        *(u16*)((char*)Pw + rloc * 128 + (cbyte ^ ((rloc & 7) << 4))) =
            f32_to_bf16(p);
      }
    }
    // ---- read P as A-fragments (same-wave RAW; compiler waits lgkmcnt) ----
    bf16x8 pf0 = *(const bf16x8*)((char*)Pw + l15 * 128 +
                                  ((l4 * 16) ^ ((l15 & 7) << 4)));
    bf16x8 pf1 = *(const bf16x8*)((char*)Pw + l15 * 128 +
                                  ((64 + l4 * 16) ^ ((l15 & 7) << 4)));
    // ---- PV: V^T fragments straight from global (L2-resident) ----
#pragma unroll
    for (int nb = 0; nb < 8; ++nb) {
      const u16* vp = Vb + (long)(nb * 16 + l15) * 2048 + j0 + l4 * 8;
      bf16x8 v0 = *(const bf16x8*)(vp);
      bf16x8 v1 = *(const bf16x8*)(vp + 32);
      O[nb] = __builtin_amdgcn_mfma_f32_16x16x32_bf16(pf0, v0, O[nb], 0, 0, 0);
      O[nb] = __builtin_amdgcn_mfma_f32_16x16x32_bf16(pf1, v1, O[nb], 0, 0, 0);
    }
  }
  // ---- combine the two KV-halves of each unit via LDS (P region is dead) --
  __syncthreads();  // all waves done with P buffers
  float rsum[4];
#pragma unroll
  for (int r = 0; r < 4; ++r) {
    float v = rs[r];
    v += __shfl_xor(v, 1);
    v += __shfl_xor(v, 2);
    v += __shfl_xor(v, 4);
    v += __shfl_xor(v, 8);
    rsum[r] = v;
  }
  float* Oc = (float*)(&Pl[0][0][0]) + (unsigned)u * 2048;  // 8 KB per unit
  if (ha == 1) {
#pragma unroll
    for (int nb = 0; nb < 8; ++nb)
#pragma unroll
      for (int r = 0; r < 4; ++r)
        Oc[(l4 * 4 + r) * 128 + nb * 16 + l15] = O[nb][r];
    if (l15 == 0)
#pragma unroll
      for (int r = 0; r < 4; ++r) Rc[u * 16 + l4 * 4 + r] = rsum[r];
  }
  __syncthreads();
  if (ha == 0) {
#pragma unroll
    for (int r = 0; r < 4; ++r) {
      float inv = 1.f / (rsum[r] + Rc[u * 16 + l4 * 4 + r]);
      int i = irow + r;
      u16* op = Oa + ((long)bb * 2048 + i) * 2048 + h * 128;
#pragma unroll
      for (int nb = 0; nb < 8; ++nb)
        op[nb * 16 + l15] =
            f32_to_bf16((O[nb][r] + Oc[(l4 * 4 + r) * 128 + nb * 16 + l15]) * inv);
    }
  }
}

extern "C" void kernel_launch(void* const* d_in, const int* in_sizes, int n_in,
                              void* d_out, int out_size, void* d_ws, size_t ws_size,
                              hipStream_t stream) {
  const float* x = (const float*)d_in[0];
  const float* Wqkv = (const float*)d_in[1];
  const float* bqkv = (const float*)d_in[2];
  const float* Wo = (const float*)d_in[3];
  const float* bo = (const float*)d_in[4];
  float* out = (float*)d_out;

  char* ws = (char*)d_ws;
  u16* xb = (u16*)(ws);
  u16* VTb = (u16*)(ws);  // aliases xb (xb dead after GEMM1)
  u16* WqkvT = (u16*)(ws + 16777216);
  u16* attn_out = (u16*)(ws + 16777216);  // aliases WqkvT (dead after GEMM1)
  u16* WoT = (u16*)(ws + 16777216 + 25165824);
  u16* Qb = (u16*)(ws + 50331648);
  u16* Kb = (u16*)(ws + 67108864);
  u16* Vb = (u16*)(ws + 83886080);

  k_convert<<<8192, 256, 0, stream>>>(x, xb, 8388608 / 4);
  k_transpose_w<<<dim3(192, 64), 256, 0, stream>>>(Wqkv, WqkvT, 2048, 6144);
  k_transpose_w<<<dim3(64, 64), 256, 0, stream>>>(Wo, WoT, 2048, 2048);
  k_gemm<0><<<dim3(32, 48), 256, 0, stream>>>(xb, WqkvT, bqkv, Qb, Kb, Vb,
                                              nullptr, 4096, 6144, 2048);
  k_transpose_v<<<dim3(64, 4, 32), 256, 0, stream>>>(Vb, VTb);
  k_attn<<<dim3(2048), 256, 0, stream>>>(Qb, Kb, VTb, attn_out);
  k_gemm<1><<<dim3(32, 16), 256, 0, stream>>>(attn_out, WoT, bo, nullptr,
                                              nullptr, nullptr, out, 4096, 2048,
                                              2048);
}

// Round 7
// 289.374 us; speedup vs baseline: 1.7983x; 1.5984x over previous
//
#include <hip/hip_runtime.h>

typedef __attribute__((ext_vector_type(4))) float f32x4;
typedef __attribute__((ext_vector_type(8))) __bf16 bf16x8;
typedef unsigned short u16;

#define GAS(p) ((const __attribute__((address_space(1))) void*)(p))
#define LAS(p) ((__attribute__((address_space(3))) void*)(p))

__device__ __forceinline__ u16 f32_to_bf16(float f) {
  unsigned u = __builtin_bit_cast(unsigned, f);
  u += 0x7FFFu + ((u >> 16) & 1u);
  return (u16)(u >> 16);
}

// ---------------- elementwise f32 -> bf16 ----------------
__global__ __launch_bounds__(256) void k_convert(const float* __restrict__ X,
                                                 u16* __restrict__ Y, int n4) {
  int i = blockIdx.x * 256 + threadIdx.x;
  if (i >= n4) return;
  float4 v = ((const float4*)X)[i];
  ushort4 r;
  r.x = f32_to_bf16(v.x); r.y = f32_to_bf16(v.y);
  r.z = f32_to_bf16(v.z); r.w = f32_to_bf16(v.w);
  ((ushort4*)Y)[i] = r;
}

// ---------------- W [K][N] f32 -> WT [N][K] bf16 ----------------
__global__ __launch_bounds__(256) void k_transpose_w(const float* __restrict__ W,
                                                     u16* __restrict__ WT,
                                                     int K, int N) {
  __shared__ float tile[32][33];
  int n0 = blockIdx.x * 32, k0 = blockIdx.y * 32;
  int tx = threadIdx.x & 31, ty = threadIdx.x >> 5;
#pragma unroll
  for (int r = 0; r < 4; ++r)
    tile[ty + r * 8][tx] = W[(long)(k0 + ty + r * 8) * N + n0 + tx];
  __syncthreads();
#pragma unroll
  for (int r = 0; r < 4; ++r)
    WT[(long)(n0 + ty + r * 8) * K + k0 + tx] = f32_to_bf16(tile[tx][ty + r * 8]);
}

// ---------------- V [BH][S][128] bf16 -> VT [BH][128][S] bf16 ----------------
__global__ __launch_bounds__(256) void k_transpose_v(const u16* __restrict__ V,
                                                     u16* __restrict__ VT) {
  __shared__ u16 tile[32][34];
  int s0 = blockIdx.x * 32, d0 = blockIdx.y * 32, bh = blockIdx.z;
  int tx = threadIdx.x & 31, ty = threadIdx.x >> 5;
  const u16* Vb = V + (long)bh * 2048 * 128;
  u16* VTb = VT + (long)bh * 128 * 2048;
#pragma unroll
  for (int r = 0; r < 4; ++r)
    tile[ty + r * 8][tx] = Vb[(long)(s0 + ty + r * 8) * 128 + d0 + tx];
  __syncthreads();
#pragma unroll
  for (int r = 0; r < 4; ++r)
    VTb[(long)(d0 + ty + r * 8) * 2048 + s0 + tx] = tile[tx][ty + r * 8];
}

// ---------------- m97-structure bf16 GEMM, 128x128 tile, BK=32 ----------------
template <int EPI>
__global__ __launch_bounds__(256) void k_gemm(
    const u16* __restrict__ A, const u16* __restrict__ BT,
    const float* __restrict__ bias,
    u16* __restrict__ Qo, u16* __restrict__ Ko, u16* __restrict__ Vo,
    float* __restrict__ Cout, int M, int N, int K) {
  __shared__ alignas(16) u16 As[128 * 32];
  __shared__ alignas(16) u16 Bs[128 * 32];
  const int t = threadIdx.x;
  const int wave = t >> 6, lane = t & 63;
  const int wr = wave >> 1, wc = wave & 1;
  const int l15 = lane & 15, l4 = lane >> 4;
  const int brow = blockIdx.x * 128, bcol = blockIdx.y * 128;

  const f32x4 fzero = {0.f, 0.f, 0.f, 0.f};
  f32x4 acc[4][4];
#pragma unroll
  for (int m = 0; m < 4; ++m)
#pragma unroll
    for (int n = 0; n < 4; ++n) acc[m][n] = fzero;

  const int c0 = wave * 64 + lane;
  const int c1 = 256 + c0;
  const u16* ga0 = A + (long)(brow + (c0 >> 2)) * K + (c0 & 3) * 8;
  const u16* ga1 = A + (long)(brow + (c1 >> 2)) * K + (c1 & 3) * 8;
  const u16* gb0 = BT + (long)(bcol + (c0 >> 2)) * K + (c0 & 3) * 8;
  const u16* gb1 = BT + (long)(bcol + (c1 >> 2)) * K + (c1 & 3) * 8;
  char* lA0 = (char*)As + (wave * 64) * 16;
  char* lA1 = (char*)As + (256 + wave * 64) * 16;
  char* lB0 = (char*)Bs + (wave * 64) * 16;
  char* lB1 = (char*)Bs + (256 + wave * 64) * 16;

  for (int k0 = 0; k0 < K; k0 += 32) {
    __builtin_amdgcn_global_load_lds(GAS(ga0 + k0), LAS(lA0), 16, 0, 0);
    __builtin_amdgcn_global_load_lds(GAS(ga1 + k0), LAS(lA1), 16, 0, 0);
    __builtin_amdgcn_global_load_lds(GAS(gb0 + k0), LAS(lB0), 16, 0, 0);
    __builtin_amdgcn_global_load_lds(GAS(gb1 + k0), LAS(lB1), 16, 0, 0);
    __syncthreads();
    bf16x8 af[4], bf[4];
#pragma unroll
    for (int m = 0; m < 4; ++m)
      af[m] = *(const bf16x8*)(As + (wr * 64 + m * 16 + l15) * 32 + l4 * 8);
#pragma unroll
    for (int n = 0; n < 4; ++n)
      bf[n] = *(const bf16x8*)(Bs + (wc * 64 + n * 16 + l15) * 32 + l4 * 8);
#pragma unroll
    for (int m = 0; m < 4; ++m)
#pragma unroll
      for (int n = 0; n < 4; ++n)
        acc[m][n] =
            __builtin_amdgcn_mfma_f32_16x16x32_bf16(af[m], bf[n], acc[m][n], 0, 0, 0);
    __syncthreads();
  }

  if (EPI == 0) {
    const int which = bcol >> 11;
    u16* dst = (which == 0) ? Qo : (which == 1) ? Ko : Vo;
    const int cbase = bcol & 2047;
#pragma unroll
    for (int n = 0; n < 4; ++n) {
      int col = cbase + wc * 64 + n * 16 + l15;
      int h = col >> 7, d = col & 127;
      float bv = bias[bcol + wc * 64 + n * 16 + l15];
#pragma unroll
      for (int m = 0; m < 4; ++m) {
#pragma unroll
        for (int r = 0; r < 4; ++r) {
          int row = brow + wr * 64 + m * 16 + l4 * 4 + r;
          int b = row >> 11, s = row & 2047;
          dst[(((long)(b * 16 + h)) * 2048 + s) * 128 + d] =
              f32_to_bf16(acc[m][n][r] + bv);
        }
      }
    }
  } else {
#pragma unroll
    for (int m = 0; m < 4; ++m) {
#pragma unroll
      for (int r = 0; r < 4; ++r) {
        int row = brow + wr * 64 + m * 16 + l4 * 4 + r;
#pragma unroll
        for (int n = 0; n < 4; ++n) {
          int col = bcol + wc * 64 + n * 16 + l15;
          Cout[(long)row * N + col] = acc[m][n][r] + bias[col];
        }
      }
    }
  }
}

// ---------------- flash attention with ALiBi, causal ----------------
// Block = 4 waves sharing ONE 64-row q-tile of one bh (wave w owns rows
// w*16..w*16+15). K and V^T tiles (KVBLK=64) are staged in LDS, DOUBLE-
// BUFFERED, via global_load_lds, shared by all 4 waves (4x fewer L2 reads
// than per-wave fetching; LDS latency on the critical path instead of L2).
// Swizzle (rule #21, both-sides): LDS layout is linear; the 16B chunk at
// slot (row, s) holds GLOBAL chunk (row, s ^ (row&7)) — achieved by pre-
// swizzling the per-lane global SOURCE address; reads apply the same XOR.
// This makes all ds_read_b128 minimum-cycle (chunk' mod 8 uniform).
// Softmax: fixed m=0 (exact here: scores are O(+-10) in log2 units; f32
// exp2 can't overflow, masked entries underflow to 0); per-lane partial
// sums, one shuffle-reduce in the epilogue.
// grid = 1024: bh = b&31 (b%8=bh%8 -> same-bh same XCD), qt = 31-(b>>5)
// heavy-first LPT over 512 resident slots (2 blocks/CU at 72KB LDS).
// All 4 waves iterate jt=0..qt uniformly (barrier-safe).
__global__ __launch_bounds__(256, 4) void k_attn(const u16* __restrict__ Q,
                                                 const u16* __restrict__ Kp,
                                                 const u16* __restrict__ VT,
                                                 u16* __restrict__ Oa) {
  __shared__ alignas(16) u16 Kl[2][64 * 128];  // 2 x 16KB, [64 rows][16 chunks]
  __shared__ alignas(16) u16 Vl[2][128 * 64];  // 2 x 16KB, [128 rows][8 chunks]
  __shared__ alignas(16) u16 Pl[4][16 * 64];   // per-wave P, 8KB
  const int b = blockIdx.x;
  const int bh = b & 31;
  const int qt = 31 - (b >> 5);  // 64-row q-tile, heavy-first
  const int bb = bh >> 4, h = bh & 15;
  const int wave = threadIdx.x >> 6, lane = threadIdx.x & 63;
  const int l15 = lane & 15, l4 = lane >> 4;
  const int l7 = lane & 7, l8 = lane >> 3;  // for V staging
  const float LOG2E = 1.4426950408889634f;
  const float scale = 0.08838834764831845f * LOG2E;  // (1/sqrt(128))*log2e
  const float slope = exp2f(-0.5f * (float)h) * LOG2E;

  const int q0 = qt * 64 + wave * 16;
  const u16* Qb = Q + ((long)bh * 2048 + q0 + l15) * 128;
  bf16x8 qf[4];
#pragma unroll
  for (int kk = 0; kk < 4; ++kk) qf[kk] = *(const bf16x8*)(Qb + kk * 32 + l4 * 8);

  const u16* Kb = Kp + (long)bh * 2048 * 128;
  const u16* VTb = VT + (long)bh * 128 * 2048;

  // stage K tile jt into Kl[buf]: 16KB = 16 wave-chunks of 1KB; wave w takes
  // wave-chunks {w, w+4, w+8, w+12}. Lane l of wave-chunk wc writes LDS
  // bytes wc*1024 + l*16 (linear, HW-added), i.e. tile (row=wc*4+l4, slot=l15);
  // source = global chunk (row, l15 ^ (row&7)).
  auto stageK = [&](int jt, int buf) {
#pragma unroll
    for (int g = 0; g < 4; ++g) {
      const int wc = g * 4 + wave;
      const int row = wc * 4 + l4;
      const u16* src = Kb + (long)(jt * 64 + row) * 128 + ((l15 ^ (row & 7)) * 8);
      __builtin_amdgcn_global_load_lds(GAS(src), LAS(&Kl[buf][wc * 512]), 16, 0, 0);
    }
  };
  // stage V^T tile jt: [128 rows][8 slots of 16B]; wave-chunk wc covers rows
  // wc*8..wc*8+7; lane l -> (row=wc*8+l8, slot=l7); source chunk = l7 ^ l8.
  auto stageV = [&](int jt, int buf) {
#pragma unroll
    for (int g = 0; g < 4; ++g) {
      const int wc = g * 4 + wave;
      const int d = wc * 8 + l8;
      const u16* src = VTb + (long)d * 2048 + jt * 64 + ((l7 ^ l8) * 8);
      __builtin_amdgcn_global_load_lds(GAS(src), LAS(&Vl[buf][wc * 512]), 16, 0, 0);
    }
  };

  float rs[4];  // per-lane partial row-sums
  f32x4 O[8];
  const f32x4 fzero = {0.f, 0.f, 0.f, 0.f};
#pragma unroll
  for (int r = 0; r < 4; ++r) rs[r] = 0.f;
#pragma unroll
  for (int nb = 0; nb < 8; ++nb) O[nb] = fzero;

  u16* Pw = Pl[wave];
  const int irow = q0 + l4 * 4;  // this lane's 4 rows are irow+r
  const int sw = l15 & 7;        // read-side XOR key (row&7 == l15&7)

  stageK(0, 0);
  stageV(0, 0);
  __syncthreads();  // drains vmcnt, all waves see tile 0

  for (int jt = 0; jt <= qt; ++jt) {
    const int cur = jt & 1;
    if (jt < qt) {  // prefetch next tile; overlaps with this iteration
      stageK(jt + 1, cur ^ 1);
      stageV(jt + 1, cur ^ 1);
    }
    const u16* Kc = Kl[cur];
    const u16* Vc = Vl[cur];
    const int j0 = jt * 64;
    // ---- QK^T -> P = exp2(s*scale' - slope'*(i-j)) straight to LDS ----
#pragma unroll
    for (int cb = 0; cb < 4; ++cb) {
      f32x4 sa = fzero;
      const u16* kp = Kc + (cb * 16 + l15) * 128;
#pragma unroll
      for (int kk = 0; kk < 4; ++kk) {
        bf16x8 kf = *(const bf16x8*)(kp + (((kk * 4 + l4) ^ sw) * 8));
        sa = __builtin_amdgcn_mfma_f32_16x16x32_bf16(qf[kk], kf, sa, 0, 0, 0);
      }
      const int j = j0 + cb * 16 + l15;
#pragma unroll
      for (int r = 0; r < 4; ++r) {
        int i = irow + r;
        float s = sa[r] * scale - slope * (float)(i - j);
        float p = __builtin_amdgcn_exp2f((j <= i) ? s : -1e30f);
        rs[r] += p;
        int rloc = l4 * 4 + r;
        int cbyte = (cb * 16 + l15) * 2;
        *(u16*)((char*)Pw + rloc * 128 + (cbyte ^ ((rloc & 7) << 4))) =
            f32_to_bf16(p);
      }
    }
    // ---- read P as A-fragments (same-wave RAW; compiler waits lgkmcnt) ----
    bf16x8 pf0 = *(const bf16x8*)((char*)Pw + l15 * 128 +
                                  ((l4 * 16) ^ ((l15 & 7) << 4)));
    bf16x8 pf1 = *(const bf16x8*)((char*)Pw + l15 * 128 +
                                  ((64 + l4 * 16) ^ ((l15 & 7) << 4)));
    // ---- PV from swizzled V^T LDS tile ----
#pragma unroll
    for (int nb = 0; nb < 8; ++nb) {
      const u16* vp = Vc + (nb * 16 + l15) * 64;
      bf16x8 v0 = *(const bf16x8*)(vp + ((l4 ^ sw) * 8));
      bf16x8 v1 = *(const bf16x8*)(vp + (((4 + l4) ^ sw) * 8));
      O[nb] = __builtin_amdgcn_mfma_f32_16x16x32_bf16(pf0, v0, O[nb], 0, 0, 0);
      O[nb] = __builtin_amdgcn_mfma_f32_16x16x32_bf16(pf1, v1, O[nb], 0, 0, 0);
    }
    __syncthreads();  // tile jt done everywhere; prefetch jt+1 drained
  }
  // ---- epilogue: one cross-lane sum-reduce, normalize, store ----
#pragma unroll
  for (int r = 0; r < 4; ++r) {
    float v = rs[r];
    v += __shfl_xor(v, 1);
    v += __shfl_xor(v, 2);
    v += __shfl_xor(v, 4);
    v += __shfl_xor(v, 8);
    float inv = 1.f / v;
    int i = irow + r;
    u16* op = Oa + ((long)bb * 2048 + i) * 2048 + h * 128;
#pragma unroll
    for (int nb = 0; nb < 8; ++nb) op[nb * 16 + l15] = f32_to_bf16(O[nb][r] * inv);
  }
}

extern "C" void kernel_launch(void* const* d_in, const int* in_sizes, int n_in,
                              void* d_out, int out_size, void* d_ws, size_t ws_size,
                              hipStream_t stream) {
  const float* x = (const float*)d_in[0];
  const float* Wqkv = (const float*)d_in[1];
  const float* bqkv = (const float*)d_in[2];
  const float* Wo = (const float*)d_in[3];
  const float* bo = (const float*)d_in[4];
  float* out = (float*)d_out;

  char* ws = (char*)d_ws;
  u16* xb = (u16*)(ws);
  u16* VTb = (u16*)(ws);  // aliases xb (xb dead after GEMM1)
  u16* WqkvT = (u16*)(ws + 16777216);
  u16* attn_out = (u16*)(ws + 16777216);  // aliases WqkvT (dead after GEMM1)
  u16* WoT = (u16*)(ws + 16777216 + 25165824);
  u16* Qb = (u16*)(ws + 50331648);
  u16* Kb = (u16*)(ws + 67108864);
  u16* Vb = (u16*)(ws + 83886080);

  k_convert<<<8192, 256, 0, stream>>>(x, xb, 8388608 / 4);
  k_transpose_w<<<dim3(192, 64), 256, 0, stream>>>(Wqkv, WqkvT, 2048, 6144);
  k_transpose_w<<<dim3(64, 64), 256, 0, stream>>>(Wo, WoT, 2048, 2048);
  k_gemm<0><<<dim3(32, 48), 256, 0, stream>>>(xb, WqkvT, bqkv, Qb, Kb, Vb,
                                              nullptr, 4096, 6144, 2048);
  k_transpose_v<<<dim3(64, 4, 32), 256, 0, stream>>>(Vb, VTb);
  k_attn<<<dim3(1024), 256, 0, stream>>>(Qb, Kb, VTb, attn_out);
  k_gemm<1><<<dim3(32, 16), 256, 0, stream>>>(attn_out, WoT, bo, nullptr,
                                              nullptr, nullptr, out, 4096, 2048,
                                              2048);
}

// Round 8
// 284.608 us; speedup vs baseline: 1.8284x; 1.0167x over previous
//
#include <hip/hip_runtime.h>

typedef __attribute__((ext_vector_type(4))) float f32x4;
typedef __attribute__((ext_vector_type(8))) __bf16 bf16x8;
typedef unsigned short u16;

#define GAS(p) ((const __attribute__((address_space(1))) void*)(p))
#define LAS(p) ((__attribute__((address_space(3))) void*)(p))

__device__ __forceinline__ u16 f32_to_bf16(float f) {
  unsigned u = __builtin_bit_cast(unsigned, f);
  u += 0x7FFFu + ((u >> 16) & 1u);
  return (u16)(u >> 16);
}

// ---------------- elementwise f32 -> bf16 ----------------
__global__ __launch_bounds__(256) void k_convert(const float* __restrict__ X,
                                                 u16* __restrict__ Y, int n4) {
  int i = blockIdx.x * 256 + threadIdx.x;
  if (i >= n4) return;
  float4 v = ((const float4*)X)[i];
  ushort4 r;
  r.x = f32_to_bf16(v.x); r.y = f32_to_bf16(v.y);
  r.z = f32_to_bf16(v.z); r.w = f32_to_bf16(v.w);
  ((ushort4*)Y)[i] = r;
}

// ---------------- W [K][N] f32 -> WT [N][K] bf16 ----------------
__global__ __launch_bounds__(256) void k_transpose_w(const float* __restrict__ W,
                                                     u16* __restrict__ WT,
                                                     int K, int N) {
  __shared__ float tile[32][33];
  int n0 = blockIdx.x * 32, k0 = blockIdx.y * 32;
  int tx = threadIdx.x & 31, ty = threadIdx.x >> 5;
#pragma unroll
  for (int r = 0; r < 4; ++r)
    tile[ty + r * 8][tx] = W[(long)(k0 + ty + r * 8) * N + n0 + tx];
  __syncthreads();
#pragma unroll
  for (int r = 0; r < 4; ++r)
    WT[(long)(n0 + ty + r * 8) * K + k0 + tx] = f32_to_bf16(tile[tx][ty + r * 8]);
}

// ---------------- V [BH][S][128] bf16 -> VT [BH][128][S] bf16 ----------------
__global__ __launch_bounds__(256) void k_transpose_v(const u16* __restrict__ V,
                                                     u16* __restrict__ VT) {
  __shared__ u16 tile[32][34];
  int s0 = blockIdx.x * 32, d0 = blockIdx.y * 32, bh = blockIdx.z;
  int tx = threadIdx.x & 31, ty = threadIdx.x >> 5;
  const u16* Vb = V + (long)bh * 2048 * 128;
  u16* VTb = VT + (long)bh * 128 * 2048;
#pragma unroll
  for (int r = 0; r < 4; ++r)
    tile[ty + r * 8][tx] = Vb[(long)(s0 + ty + r * 8) * 128 + d0 + tx];
  __syncthreads();
#pragma unroll
  for (int r = 0; r < 4; ++r)
    VTb[(long)(d0 + ty + r * 8) * 2048 + s0 + tx] = tile[tx][ty + r * 8];
}

// -------- 256x128 deep-pipelined bf16 GEMM, BK=64, 3 LDS buffers ----------
// T4: counted vmcnt(6) + raw s_barrier, loads stay in flight across barriers
//     (never vmcnt(0) in the main loop).  3-buffer rotation: iter t computes
//     buf t%3 and stages tile t+2 into buf (t+2)%3, whose last reader was
//     iter t-1 (barrier-separated) -> race-free by construction.
// T2: both-sides XOR swizzle (rule #21): LDS dest linear (global_load_lds),
//     global source chunk pre-XORed with row&7, ds_read XORs back ->
//     ds_read_b128 spreads over all 8 slot positions (2-way = free).
// T5: setprio(1) around each 16-MFMA cluster (two register sub-phases/K-tile).
// 8 waves (2 M x 4 N), per-wave output 128x32, acc[8][2] f32x4 = 64 VGPR.
template <int EPI>
__global__ __launch_bounds__(512, 2) void k_gemm(
    const u16* __restrict__ A, const u16* __restrict__ BT,
    const float* __restrict__ bias,
    u16* __restrict__ Qo, u16* __restrict__ Ko, u16* __restrict__ Vo,
    float* __restrict__ Cout, int M, int N, int K) {
  __shared__ alignas(16) u16 AS[3][256 * 64];  // 3 x 32 KB
  __shared__ alignas(16) u16 BS[3][128 * 64];  // 3 x 16 KB
  const int wave = threadIdx.x >> 6, lane = threadIdx.x & 63;
  const int wr = wave >> 2, wc = wave & 3;
  const int l15 = lane & 15, l4 = lane >> 4;
  const int sl = lane & 7, sr = (lane >> 3) & 7;  // staging slot / row-in-chunk

  // XCD-bijective block swizzle (all our grids have nwg % 8 == 0)
  const int nwg = gridDim.x;
  const int swz = ((int)blockIdx.x & 7) * (nwg >> 3) + ((int)blockIdx.x >> 3);
  const int mt = M >> 8;
  const int bm = swz % mt, bn = swz / mt;
  const int brow = bm * 256, bcol = bn * 128;
  const int NT = K >> 6;

  // per-lane staging sources (tile 0); slot sl will hold global chunk sl^(row&7)
  const u16* aSrc[4];
  const u16* bSrc[2];
#pragma unroll
  for (int j = 0; j < 4; ++j) {
    int row = (wave + j * 8) * 8 + (lane >> 3);
    aSrc[j] = A + (long)(brow + row) * K + ((sl ^ sr) * 8);
  }
#pragma unroll
  for (int j = 0; j < 2; ++j) {
    int row = (wave + j * 8) * 8 + (lane >> 3);
    bSrc[j] = BT + (long)(bcol + row) * K + ((sl ^ sr) * 8);
  }

  auto stage = [&](int t, int buf) {  // 6 global_load_lds dwordx4 per thread
#pragma unroll
    for (int j = 0; j < 4; ++j)
      __builtin_amdgcn_global_load_lds(GAS(aSrc[j] + t * 64),
                                       LAS(&AS[buf][(wave + j * 8) * 512]), 16, 0, 0);
#pragma unroll
    for (int j = 0; j < 2; ++j)
      __builtin_amdgcn_global_load_lds(GAS(bSrc[j] + t * 64),
                                       LAS(&BS[buf][(wave + j * 8) * 512]), 16, 0, 0);
  };

  const f32x4 fzero = {0.f, 0.f, 0.f, 0.f};
  f32x4 acc[8][2];
#pragma unroll
  for (int m = 0; m < 8; ++m)
#pragma unroll
    for (int n = 0; n < 2; ++n) acc[m][n] = fzero;

  auto compute = [&](int buf) {
    const u16* Ac = &AS[buf][0];
    const u16* Bc = &BS[buf][0];
    bf16x8 bfr[2][2];
#pragma unroll
    for (int n = 0; n < 2; ++n)
#pragma unroll
      for (int kk = 0; kk < 2; ++kk) {
        int R = wc * 32 + n * 16 + l15;
        bfr[n][kk] =
            *(const bf16x8*)(Bc + R * 64 + (((kk * 4 + l4) ^ (l15 & 7)) * 8));
      }
#pragma unroll
    for (int mh = 0; mh < 2; ++mh) {
      bf16x8 afr[4][2];
#pragma unroll
      for (int mm = 0; mm < 4; ++mm)
#pragma unroll
        for (int kk = 0; kk < 2; ++kk) {
          int R = wr * 128 + (mh * 4 + mm) * 16 + l15;
          afr[mm][kk] =
              *(const bf16x8*)(Ac + R * 64 + (((kk * 4 + l4) ^ (l15 & 7)) * 8));
        }
      __builtin_amdgcn_s_setprio(1);
#pragma unroll
      for (int mm = 0; mm < 4; ++mm)
#pragma unroll
        for (int n = 0; n < 2; ++n)
#pragma unroll
          for (int kk = 0; kk < 2; ++kk)
            acc[mh * 4 + mm][n] = __builtin_amdgcn_mfma_f32_16x16x32_bf16(
                afr[mm][kk], bfr[n][kk], acc[mh * 4 + mm][n], 0, 0, 0);
      __builtin_amdgcn_s_setprio(0);
    }
  };

  stage(0, 0);
  stage(1, 1);
  int bufc = 0;
  for (int t = 0; t < NT - 1; ++t) {
    asm volatile("s_waitcnt vmcnt(6)" ::: "memory");  // tile t landed; t+1 in flight
    __builtin_amdgcn_s_barrier();
    if (t + 2 < NT) {
      int bufn = bufc + 2;
      if (bufn >= 3) bufn -= 3;
      stage(t + 2, bufn);
    }
    compute(bufc);
    ++bufc;
    if (bufc == 3) bufc = 0;
  }
  asm volatile("s_waitcnt vmcnt(0)" ::: "memory");  // last tile
  __builtin_amdgcn_s_barrier();
  compute(bufc);

  if (EPI == 0) {
#pragma unroll
    for (int n = 0; n < 2; ++n) {
      const int col = bcol + wc * 32 + n * 16 + l15;
      const int which = col >> 11;
      u16* dst = (which == 0) ? Qo : (which == 1) ? Ko : Vo;
      const int cc = col & 2047;
      const int h = cc >> 7, d = cc & 127;
      const float bv = bias[col];
#pragma unroll
      for (int m = 0; m < 8; ++m) {
#pragma unroll
        for (int r = 0; r < 4; ++r) {
          const int row = brow + wr * 128 + m * 16 + l4 * 4 + r;  // b*2048+s
          const int bb = row >> 11, s = row & 2047;
          dst[(((long)(bb * 16 + h)) * 2048 + s) * 128 + d] =
              f32_to_bf16(acc[m][n][r] + bv);
        }
      }
    }
  } else {
#pragma unroll
    for (int m = 0; m < 8; ++m)
#pragma unroll
      for (int r = 0; r < 4; ++r) {
        const int row = brow + wr * 128 + m * 16 + l4 * 4 + r;
#pragma unroll
        for (int n = 0; n < 2; ++n) {
          const int col = bcol + wc * 32 + n * 16 + l15;
          Cout[(long)row * N + col] = acc[m][n][r] + bias[col];
        }
      }
  }
}

// ---------------- flash attention with ALiBi, causal ----------------
// (unchanged from R7 — verified; LDS-staged K/V^T, double-buffered, swizzled)
__global__ __launch_bounds__(256, 4) void k_attn(const u16* __restrict__ Q,
                                                 const u16* __restrict__ Kp,
                                                 const u16* __restrict__ VT,
                                                 u16* __restrict__ Oa) {
  __shared__ alignas(16) u16 Kl[2][64 * 128];
  __shared__ alignas(16) u16 Vl[2][128 * 64];
  __shared__ alignas(16) u16 Pl[4][16 * 64];
  const int b = blockIdx.x;
  const int bh = b & 31;
  const int qt = 31 - (b >> 5);  // heavy-first
  const int bb = bh >> 4, h = bh & 15;
  const int wave = threadIdx.x >> 6, lane = threadIdx.x & 63;
  const int l15 = lane & 15, l4 = lane >> 4;
  const int l7 = lane & 7, l8 = lane >> 3;
  const float LOG2E = 1.4426950408889634f;
  const float scale = 0.08838834764831845f * LOG2E;
  const float slope = exp2f(-0.5f * (float)h) * LOG2E;

  const int q0 = qt * 64 + wave * 16;
  const u16* Qb = Q + ((long)bh * 2048 + q0 + l15) * 128;
  bf16x8 qf[4];
#pragma unroll
  for (int kk = 0; kk < 4; ++kk) qf[kk] = *(const bf16x8*)(Qb + kk * 32 + l4 * 8);

  const u16* Kb = Kp + (long)bh * 2048 * 128;
  const u16* VTb = VT + (long)bh * 128 * 2048;

  auto stageK = [&](int jt, int buf) {
#pragma unroll
    for (int g = 0; g < 4; ++g) {
      const int wcc = g * 4 + wave;
      const int row = wcc * 4 + l4;
      const u16* src = Kb + (long)(jt * 64 + row) * 128 + ((l15 ^ (row & 7)) * 8);
      __builtin_amdgcn_global_load_lds(GAS(src), LAS(&Kl[buf][wcc * 512]), 16, 0, 0);
    }
  };
  auto stageV = [&](int jt, int buf) {
#pragma unroll
    for (int g = 0; g < 4; ++g) {
      const int wcc = g * 4 + wave;
      const int d = wcc * 8 + l8;
      const u16* src = VTb + (long)d * 2048 + jt * 64 + ((l7 ^ l8) * 8);
      __builtin_amdgcn_global_load_lds(GAS(src), LAS(&Vl[buf][wcc * 512]), 16, 0, 0);
    }
  };

  float rs[4];
  f32x4 O[8];
  const f32x4 fzero = {0.f, 0.f, 0.f, 0.f};
#pragma unroll
  for (int r = 0; r < 4; ++r) rs[r] = 0.f;
#pragma unroll
  for (int nb = 0; nb < 8; ++nb) O[nb] = fzero;

  u16* Pw = Pl[wave];
  const int irow = q0 + l4 * 4;
  const int sw = l15 & 7;

  stageK(0, 0);
  stageV(0, 0);
  __syncthreads();

  for (int jt = 0; jt <= qt; ++jt) {
    const int cur = jt & 1;
    if (jt < qt) {
      stageK(jt + 1, cur ^ 1);
      stageV(jt + 1, cur ^ 1);
    }
    const u16* Kc = Kl[cur];
    const u16* Vc = Vl[cur];
    const int j0 = jt * 64;
#pragma unroll
    for (int cb = 0; cb < 4; ++cb) {
      f32x4 sa = fzero;
      const u16* kp = Kc + (cb * 16 + l15) * 128;
#pragma unroll
      for (int kk = 0; kk < 4; ++kk) {
        bf16x8 kf = *(const bf16x8*)(kp + (((kk * 4 + l4) ^ sw) * 8));
        sa = __builtin_amdgcn_mfma_f32_16x16x32_bf16(qf[kk], kf, sa, 0, 0, 0);
      }
      const int j = j0 + cb * 16 + l15;
#pragma unroll
      for (int r = 0; r < 4; ++r) {
        int i = irow + r;
        float s = sa[r] * scale - slope * (float)(i - j);
        float p = __builtin_amdgcn_exp2f((j <= i) ? s : -1e30f);
        rs[r] += p;
        int rloc = l4 * 4 + r;
        int cbyte = (cb * 16 + l15) * 2;
        *(u16*)((char*)Pw + rloc * 128 + (cbyte ^ ((rloc & 7) << 4))) =
            f32_to_bf16(p);
      }
    }
    bf16x8 pf0 = *(const bf16x8*)((char*)Pw + l15 * 128 +
                                  ((l4 * 16) ^ ((l15 & 7) << 4)));
    bf16x8 pf1 = *(const bf16x8*)((char*)Pw + l15 * 128 +
                                  ((64 + l4 * 16) ^ ((l15 & 7) << 4)));
#pragma unroll
    for (int nb = 0; nb < 8; ++nb) {
      const u16* vp = Vc + (nb * 16 + l15) * 64;
      bf16x8 v0 = *(const bf16x8*)(vp + ((l4 ^ sw) * 8));
      bf16x8 v1 = *(const bf16x8*)(vp + (((4 + l4) ^ sw) * 8));
      O[nb] = __builtin_amdgcn_mfma_f32_16x16x32_bf16(pf0, v0, O[nb], 0, 0, 0);
      O[nb] = __builtin_amdgcn_mfma_f32_16x16x32_bf16(pf1, v1, O[nb], 0, 0, 0);
    }
    __syncthreads();
  }
#pragma unroll
  for (int r = 0; r < 4; ++r) {
    float v = rs[r];
    v += __shfl_xor(v, 1);
    v += __shfl_xor(v, 2);
    v += __shfl_xor(v, 4);
    v += __shfl_xor(v, 8);
    float inv = 1.f / v;
    int i = irow + r;
    u16* op = Oa + ((long)bb * 2048 + i) * 2048 + h * 128;
#pragma unroll
    for (int nb = 0; nb < 8; ++nb) op[nb * 16 + l15] = f32_to_bf16(O[nb][r] * inv);
  }
}

extern "C" void kernel_launch(void* const* d_in, const int* in_sizes, int n_in,
                              void* d_out, int out_size, void* d_ws, size_t ws_size,
                              hipStream_t stream) {
  const float* x = (const float*)d_in[0];
  const float* Wqkv = (const float*)d_in[1];
  const float* bqkv = (const float*)d_in[2];
  const float* Wo = (const float*)d_in[3];
  const float* bo = (const float*)d_in[4];
  float* out = (float*)d_out;

  char* ws = (char*)d_ws;
  u16* xb = (u16*)(ws);
  u16* VTb = (u16*)(ws);  // aliases xb (xb dead after GEMM1)
  u16* WqkvT = (u16*)(ws + 16777216);
  u16* attn_out = (u16*)(ws + 16777216);  // aliases WqkvT (dead after GEMM1)
  u16* WoT = (u16*)(ws + 16777216 + 25165824);
  u16* Qb = (u16*)(ws + 50331648);
  u16* Kb = (u16*)(ws + 67108864);
  u16* Vb = (u16*)(ws + 83886080);

  k_convert<<<8192, 256, 0, stream>>>(x, xb, 8388608 / 4);
  k_transpose_w<<<dim3(192, 64), 256, 0, stream>>>(Wqkv, WqkvT, 2048, 6144);
  k_transpose_w<<<dim3(64, 64), 256, 0, stream>>>(Wo, WoT, 2048, 2048);
  // GEMM1: M=4096, N=6144 -> grid 16 x 48 = 768 blocks (3/CU), 512 thr
  k_gemm<0><<<dim3(768), 512, 0, stream>>>(xb, WqkvT, bqkv, Qb, Kb, Vb,
                                           nullptr, 4096, 6144, 2048);
  k_transpose_v<<<dim3(64, 4, 32), 256, 0, stream>>>(Vb, VTb);
  k_attn<<<dim3(1024), 256, 0, stream>>>(Qb, Kb, VTb, attn_out);
  // GEMM2: M=4096, N=2048 -> grid 16 x 16 = 256 blocks (1/CU)
  k_gemm<1><<<dim3(256), 512, 0, stream>>>(attn_out, WoT, bo, nullptr,
                                           nullptr, nullptr, out, 4096, 2048,
                                           2048);
}